// Round 10
// baseline (470.625 us; speedup 1.0000x reference)
//
#include <hip/hip_runtime.h>
#include <math.h>

#define D_IN 256
#define HID 128
#define D_OUT 64
#define NEG_SLOPE 0.2f

typedef short short8 __attribute__((ext_vector_type(8)));
typedef float floatx4 __attribute__((ext_vector_type(4)));

__device__ __forceinline__ float wave_reduce_sum(float v) {
    #pragma unroll
    for (int off = 32; off > 0; off >>= 1) v += __shfl_xor(v, off, 64);
    return v;
}
__device__ __forceinline__ int wave_reduce_sum_i(int v) {
    #pragma unroll
    for (int off = 32; off > 0; off >>= 1) v += __shfl_xor(v, off, 64);
    return v;
}
__device__ __forceinline__ int wave_scan_incl_i(int v) {
    int lane = threadIdx.x & 63;
    #pragma unroll
    for (int off = 1; off < 64; off <<= 1) {
        int t = __shfl_up(v, off, 64);
        if (lane >= off) v += t;
    }
    return v;
}

__device__ __forceinline__ short f2bf(float f) {           // RNE f32->bf16
    unsigned u = __float_as_uint(f);
    u += 0x7fffu + ((u >> 16) & 1u);
    return (short)(u >> 16);
}
__device__ __forceinline__ unsigned pk2(float a, float b) {
    return (unsigned)(unsigned short)f2bf(a) | ((unsigned)(unsigned short)f2bf(b) << 16);
}
__device__ __forceinline__ float bflo(unsigned p) { return __uint_as_float(p << 16); }
__device__ __forceinline__ float bfhi(unsigned p) { return __uint_as_float(p & 0xffff0000u); }

// ---------- device bodies for fused dispatch ----------
__device__ void prep_body(const float* Wsrc1, const float* att_src1,
                          const float* Wdst1, const float* att_dst1,
                          const float* Wsrc2, const float* att_src2,
                          const float* Wdst2, const float* att_dst2,
                          const float* b1, const float* b_lin1,
                          const float* b2, const float* b_lin2,
                          float* v_src1, float* v_dst1, float* v_src2, float* v_dst2,
                          float* bsum1, float* bsum2) {
    int t = threadIdx.x;
    if (t < D_IN) {
        float s1 = 0.f, s2 = 0.f;
        for (int c = 0; c < HID; c++) {
            s1 += Wsrc1[t * HID + c] * att_src1[c];
            s2 += Wdst1[t * HID + c] * att_dst1[c];
        }
        v_src1[t] = s1; v_dst1[t] = s2;
    }
    if (t < HID) {
        float s1 = 0.f, s2 = 0.f;
        for (int c = 0; c < D_OUT; c++) {
            s1 += Wsrc2[t * D_OUT + c] * att_src2[c];
            s2 += Wdst2[t * D_OUT + c] * att_dst2[c];
        }
        v_src2[t] = s1; v_dst2[t] = s2;
        bsum1[t] = b1[t] + b_lin1[t];
    }
    if (t < D_OUT) bsum2[t] = b2[t] + b_lin2[t];
}

__device__ void pack_body(const float* Wa, const float* Wb, short* Wp,
                          int NTG, int NH, int total, int idx) {
    if (idx >= total) return;
    int j = idx & 7;
    int lane = (idx >> 3) & 63;
    int r = idx >> 9;
    int nt = r % NTG;
    int s = r / NTG;
    int k = s * 32 + ((lane >> 4) * 8) + j;
    int cg = nt * 16 + (lane & 15);
    const float* W = (cg < NH) ? Wa : Wb;
    int col = (cg < NH) ? cg : cg - NH;
    Wp[idx] = f2bf(W[(size_t)k * NH + col]);
}

// ---- fused: hist | pack1 | pack2 | prep ----
__global__ void fused_pre(const int* __restrict__ dst, int E, int* deg, int EB,
                          const float* W_src1, const float* W_lin1, short* Wp1,
                          const float* W_src2, const float* W_lin2, short* Wp2,
                          const float* att_src1, const float* W_dst1, const float* att_dst1,
                          const float* att_src2, const float* W_dst2, const float* att_dst2,
                          const float* b1, const float* b_lin1,
                          const float* b2, const float* b_lin2,
                          float* v_src1, float* v_dst1, float* v_src2, float* v_dst2,
                          float* bsum1, float* bsum2) {
    int bid = blockIdx.x;
    if (bid < EB) {
        int e = bid * 256 + threadIdx.x;
        if (e < E) atomicAdd(&deg[dst[e]], 1);
    } else if (bid < EB + 256) {
        pack_body(W_src1, W_lin1, Wp1, 16, HID, 8 * 16 * 512, (bid - EB) * 256 + threadIdx.x);
    } else if (bid < EB + 320) {
        pack_body(W_src2, W_lin2, Wp2, 8, D_OUT, 4 * 8 * 512, (bid - EB - 256) * 256 + threadIdx.x);
    } else {
        prep_body(W_src1, att_src1, W_dst1, att_dst1, W_src2, att_src2, W_dst2, att_dst2,
                  b1, b_lin1, b2, b_lin2, v_src1, v_dst1, v_src2, v_dst2, bsum1, bsum2);
    }
}

// ---- CSR scan ----
__global__ void scan_partial(const int* __restrict__ deg, int n, int* bsums) {
    __shared__ int ws[16];
    int i = blockIdx.x * 1024 + threadIdx.x;
    int v = (i < n) ? deg[i] : 0;
    int s = wave_reduce_sum_i(v);
    if ((threadIdx.x & 63) == 0) ws[threadIdx.x >> 6] = s;
    __syncthreads();
    if (threadIdx.x == 0) {
        int tot = 0;
        #pragma unroll
        for (int w = 0; w < 16; w++) tot += ws[w];
        bsums[blockIdx.x] = tot;
    }
}

__global__ void scan_offsets(const int* __restrict__ bsums, int nb, int* boff) {
    int lane = threadIdx.x;
    int v = (lane < nb) ? bsums[lane] : 0;
    int incl = wave_scan_incl_i(v);
    if (lane < nb) boff[lane] = incl - v;
}

__global__ void scan_final(const int* __restrict__ deg, int n, const int* __restrict__ boff,
                           int* row_ptr, int* cursor) {
    __shared__ int ws[16];
    int i = blockIdx.x * 1024 + threadIdx.x;
    int wid = threadIdx.x >> 6;
    int v = (i < n) ? deg[i] : 0;
    int sv = wave_scan_incl_i(v);
    if ((threadIdx.x & 63) == 63) ws[wid] = sv;
    __syncthreads();
    if (threadIdx.x == 0) {
        int run = 0;
        #pragma unroll
        for (int w = 0; w < 16; w++) { int t = ws[w]; ws[w] = run; run += t; }
    }
    __syncthreads();
    int excl = boff[blockIdx.x] + ws[wid] + sv - v;
    if (i < n) {
        row_ptr[i] = excl; cursor[i] = excl;
        if (i == n - 1) row_ptr[n] = excl + v;
    }
}

// ---- fused: scatter (ushort ssrc) INTERLEAVED with gemm1 (fp32 A + att dots) ----
// Block mapping: g = bid/5, r = bid%5. r==0 -> gemm block g (g < MB); else
// scatter block g*4 + r - 1. Interleave keeps a gemm:scatter mix resident per CU
// so the scatter's random-write drain hides under MFMA/VALU.
__global__ __launch_bounds__(256, 3) void fused_big(
        const int* __restrict__ src, const int* __restrict__ dst, int E,
        int* cursor, unsigned short* __restrict__ ssrc,
        const float* __restrict__ X, const short* __restrict__ Wp,
        const float* __restrict__ bias,
        const float* __restrict__ vsrc, const float* __restrict__ vdst,
        float* __restrict__ a_src, float* __restrict__ a_dst,
        unsigned short* __restrict__ outb, unsigned short* __restrict__ outc,
        int M, int MB) {
    int g = blockIdx.x / 5, r = blockIdx.x % 5;
    if (r != 0) {
        int e = (g * 4 + r - 1) * 256 + threadIdx.x;
        if (e < E) {
            int d = dst[e];
            int pos = atomicAdd(&cursor[d], 1);
            ssrc[pos] = (unsigned short)src[e];
        }
        return;
    }
    // ---- gemm block g: 64 rows x 256 logical cols, KS=8, NT=4 ----
    const int K = 256, NTG = 16, NH = 128;
    int tid = threadIdx.x;
    int wave = tid >> 6, lane = tid & 63;
    int mr = lane & 15, quad = lane >> 4;
    int bm = g * 64;

    floatx4 acc[4][4];
    #pragma unroll
    for (int i = 0; i < 4; i++)
        #pragma unroll
        for (int j = 0; j < 4; j++) acc[i][j] = (floatx4){0.f, 0.f, 0.f, 0.f};

    const float* arow[4];
    #pragma unroll
    for (int tm = 0; tm < 4; tm++) {
        int gr = bm + tm * 16 + mr;
        if (gr >= M) gr = M - 1;
        arow[tm] = X + (size_t)gr * K + quad * 8;
    }
    const short* bbase = Wp + ((size_t)(wave * 4) * 64 + lane) * 8;
    float psrc[4] = {0.f, 0.f, 0.f, 0.f}, pdst[4] = {0.f, 0.f, 0.f, 0.f};

    #pragma unroll
    for (int s = 0; s < 8; s++) {
        float4 vsa = *(const float4*)(vsrc + s * 32 + quad * 8);
        float4 vsb = *(const float4*)(vsrc + s * 32 + quad * 8 + 4);
        float4 vda = *(const float4*)(vdst + s * 32 + quad * 8);
        float4 vdb = *(const float4*)(vdst + s * 32 + quad * 8 + 4);
        short8 af[4], bf[4];
        #pragma unroll
        for (int tm = 0; tm < 4; tm++) {
            float4 f0 = *(const float4*)(arow[tm] + s * 32);
            float4 f1 = *(const float4*)(arow[tm] + s * 32 + 4);
            psrc[tm] += f0.x * vsa.x + f0.y * vsa.y + f0.z * vsa.z + f0.w * vsa.w
                      + f1.x * vsb.x + f1.y * vsb.y + f1.z * vsb.z + f1.w * vsb.w;
            pdst[tm] += f0.x * vda.x + f0.y * vda.y + f0.z * vda.z + f0.w * vda.w
                      + f1.x * vdb.x + f1.y * vdb.y + f1.z * vdb.z + f1.w * vdb.w;
            af[tm] = short8{f2bf(f0.x), f2bf(f0.y), f2bf(f0.z), f2bf(f0.w),
                            f2bf(f1.x), f2bf(f1.y), f2bf(f1.z), f2bf(f1.w)};
        }
        #pragma unroll
        for (int tn = 0; tn < 4; tn++)
            bf[tn] = *(const short8*)(bbase + ((size_t)s * NTG + tn) * 512);
        #pragma unroll
        for (int tn = 0; tn < 4; tn++)
            #pragma unroll
            for (int tm = 0; tm < 4; tm++)
                acc[tm][tn] = __builtin_amdgcn_mfma_f32_16x16x32_bf16(af[tm], bf[tn],
                                                                      acc[tm][tn], 0, 0, 0);
    }

    #pragma unroll
    for (int tm = 0; tm < 4; tm++) {
        float ps = psrc[tm], pd = pdst[tm];
        ps += __shfl_xor(ps, 16, 64); ps += __shfl_xor(ps, 32, 64);
        pd += __shfl_xor(pd, 16, 64); pd += __shfl_xor(pd, 32, 64);
        int gr = bm + tm * 16 + mr;
        if (quad == 0 && gr < M) { a_src[gr] = ps; a_dst[gr] = pd; }
    }

    #pragma unroll
    for (int tm = 0; tm < 4; tm++) {
        #pragma unroll
        for (int tn = 0; tn < 4; tn++) {
            int cg = wave * 64 + tn * 16 + mr;
            if (cg < NH) {
                #pragma unroll
                for (int rr = 0; rr < 4; rr++) {
                    int gr = bm + tm * 16 + quad * 4 + rr;
                    if (gr < M)
                        outb[(size_t)gr * NH + cg] = (unsigned short)f2bf(acc[tm][tn][rr]);
                }
            } else {
                float bv = bias[cg - NH];
                #pragma unroll
                for (int rr = 0; rr < 4; rr++) {
                    int gr = bm + tm * 16 + quad * 4 + rr;
                    if (gr < M)
                        outc[(size_t)gr * NH + (cg - NH)] = (unsigned short)f2bf(acc[tm][tn][rr] + bv);
                }
            }
        }
    }
}

// ---- barrier-free direct-fragment MFMA GEMM, bf16 A (layer 2) ----
template <int KS, int NT>
__global__ __launch_bounds__(256, 3) void gemm_direct(const unsigned short* __restrict__ A,
                                                      const short* __restrict__ Wp,
                                                      const float* __restrict__ bias,
                                                      unsigned short* __restrict__ outb,
                                                      unsigned short* __restrict__ outc, int M) {
    const int K = KS * 32;
    const int NTG = 4 * NT;
    const int NH = NT * 32;
    int tid = threadIdx.x;
    int wave = tid >> 6, lane = tid & 63;
    int mr = lane & 15, quad = lane >> 4;
    int bm = blockIdx.x * 64;

    floatx4 acc[4][NT];
    #pragma unroll
    for (int i = 0; i < 4; i++)
        #pragma unroll
        for (int j = 0; j < NT; j++) acc[i][j] = (floatx4){0.f, 0.f, 0.f, 0.f};

    const unsigned short* arow[4];
    #pragma unroll
    for (int tm = 0; tm < 4; tm++) {
        int gr = bm + tm * 16 + mr;
        if (gr >= M) gr = M - 1;
        arow[tm] = A + (size_t)gr * K + quad * 8;
    }
    const short* bbase = Wp + ((size_t)(wave * NT) * 64 + lane) * 8;

    #pragma unroll
    for (int s = 0; s < KS; s++) {
        short8 af[4], bf[NT];
        #pragma unroll
        for (int tm = 0; tm < 4; tm++)
            af[tm] = *(const short8*)(arow[tm] + s * 32);
        #pragma unroll
        for (int tn = 0; tn < NT; tn++)
            bf[tn] = *(const short8*)(bbase + ((size_t)s * NTG + tn) * 512);
        #pragma unroll
        for (int tn = 0; tn < NT; tn++)
            #pragma unroll
            for (int tm = 0; tm < 4; tm++)
                acc[tm][tn] = __builtin_amdgcn_mfma_f32_16x16x32_bf16(af[tm], bf[tn],
                                                                      acc[tm][tn], 0, 0, 0);
    }

    #pragma unroll
    for (int tm = 0; tm < 4; tm++) {
        #pragma unroll
        for (int tn = 0; tn < NT; tn++) {
            int cg = wave * NT * 16 + tn * 16 + mr;
            if (cg < NH) {
                #pragma unroll
                for (int r = 0; r < 4; r++) {
                    int gr = bm + tm * 16 + quad * 4 + r;
                    if (gr < M)
                        outb[(size_t)gr * NH + cg] = (unsigned short)f2bf(acc[tm][tn][r]);
                }
            } else {
                float bv = bias[cg - NH];
                #pragma unroll
                for (int r = 0; r < 4; r++) {
                    int gr = bm + tm * 16 + quad * 4 + r;
                    if (gr < M)
                        outc[(size_t)gr * NH + (cg - NH)] = (unsigned short)f2bf(acc[tm][tn][r] + bv);
                }
            }
        }
    }
}

// ---- layer-1 agg: quarter-wave per edge, uint4 gathers, ushort ssrc ----
__global__ void agg1_kernel(const int* __restrict__ row_ptr, const unsigned short* __restrict__ ssrc,
                            const float* __restrict__ a_src, const float* __restrict__ a_dst,
                            const unsigned short* __restrict__ h1b,
                            const unsigned short* __restrict__ linb,
                            const float* __restrict__ vs2, const float* __restrict__ vd2,
                            unsigned short* __restrict__ hb,
                            float* __restrict__ a_src2, float* __restrict__ a_dst2, int Nn) {
    int node = blockIdx.x * 4 + (threadIdx.x >> 6);
    int lane = threadIdx.x & 63;
    if (node >= Nn) return;
    int beg = row_ptr[node], end = row_ptr[node + 1];
    float ad = a_dst[node];

    int qh = lane >> 4, cl = lane & 15;
    float acc[8] = {0.f, 0.f, 0.f, 0.f, 0.f, 0.f, 0.f, 0.f};
    float dsum = 0.f;
    const unsigned short* hcol = h1b + cl * 8;
    int j = beg + qh;
    for (; j + 4 < end; j += 8) {
        int s0 = ssrc[j], s1 = ssrc[j + 4];
        float l0 = a_src[s0] + ad; l0 = (l0 > 0.f) ? l0 : NEG_SLOPE * l0;
        float l1 = a_src[s1] + ad; l1 = (l1 > 0.f) ? l1 : NEG_SLOPE * l1;
        float w0 = __expf(l0), w1 = __expf(l1);
        uint4 p0 = *(const uint4*)(hcol + (size_t)s0 * HID);
        uint4 p1 = *(const uint4*)(hcol + (size_t)s1 * HID);
        acc[0] += w0 * bflo(p0.x); acc[1] += w0 * bfhi(p0.x);
        acc[2] += w0 * bflo(p0.y); acc[3] += w0 * bfhi(p0.y);
        acc[4] += w0 * bflo(p0.z); acc[5] += w0 * bfhi(p0.z);
        acc[6] += w0 * bflo(p0.w); acc[7] += w0 * bfhi(p0.w);
        acc[0] += w1 * bflo(p1.x); acc[1] += w1 * bfhi(p1.x);
        acc[2] += w1 * bflo(p1.y); acc[3] += w1 * bfhi(p1.y);
        acc[4] += w1 * bflo(p1.z); acc[5] += w1 * bfhi(p1.z);
        acc[6] += w1 * bflo(p1.w); acc[7] += w1 * bfhi(p1.w);
        if (cl == 0) dsum += w0 + w1;
    }
    for (; j < end; j += 4) {
        int s0 = ssrc[j];
        float l = a_src[s0] + ad; l = (l > 0.f) ? l : NEG_SLOPE * l;
        float w = __expf(l);
        uint4 p = *(const uint4*)(hcol + (size_t)s0 * HID);
        acc[0] += w * bflo(p.x); acc[1] += w * bfhi(p.x);
        acc[2] += w * bflo(p.y); acc[3] += w * bfhi(p.y);
        acc[4] += w * bflo(p.z); acc[5] += w * bfhi(p.z);
        acc[6] += w * bflo(p.w); acc[7] += w * bfhi(p.w);
        if (cl == 0) dsum += w;
    }
    #pragma unroll
    for (int i = 0; i < 8; i++) {
        acc[i] += __shfl_xor(acc[i], 16, 64);
        acc[i] += __shfl_xor(acc[i], 32, 64);
    }
    dsum = wave_reduce_sum(dsum);
    float inv = 1.f / (dsum + 1e-16f);

    int c = cl * 8;
    uint4 lb = *(const uint4*)(linb + (size_t)node * HID + c);
    float o[8];
    o[0] = fmaxf(acc[0] * inv + bflo(lb.x), 0.f);
    o[1] = fmaxf(acc[1] * inv + bfhi(lb.x), 0.f);
    o[2] = fmaxf(acc[2] * inv + bflo(lb.y), 0.f);
    o[3] = fmaxf(acc[3] * inv + bfhi(lb.y), 0.f);
    o[4] = fmaxf(acc[4] * inv + bflo(lb.z), 0.f);
    o[5] = fmaxf(acc[5] * inv + bfhi(lb.z), 0.f);
    o[6] = fmaxf(acc[6] * inv + bflo(lb.w), 0.f);
    o[7] = fmaxf(acc[7] * inv + bfhi(lb.w), 0.f);
    if (qh == 0) {
        uint4 pk;
        pk.x = pk2(o[0], o[1]); pk.y = pk2(o[2], o[3]);
        pk.z = pk2(o[4], o[5]); pk.w = pk2(o[6], o[7]);
        *(uint4*)&hb[(size_t)node * HID + c] = pk;
    }
    float ps = 0.f, pd = 0.f;
    #pragma unroll
    for (int i = 0; i < 8; i++) { ps += o[i] * vs2[c + i]; pd += o[i] * vd2[c + i]; }
    ps = wave_reduce_sum(ps) * 0.25f;
    pd = wave_reduce_sum(pd) * 0.25f;
    if (lane == 0) { a_src2[node] = ps; a_dst2[node] = pd; }
}

// ---- layer-2 agg: eighth-wave per edge, ushort ssrc ----
__global__ void agg2_kernel(const int* __restrict__ row_ptr, const unsigned short* __restrict__ ssrc,
                            const float* __restrict__ a_src, const float* __restrict__ a_dst,
                            const unsigned short* __restrict__ h2b,
                            const unsigned short* __restrict__ lin2b,
                            float* __restrict__ out, float* __restrict__ sminv, int Nn) {
    int node = blockIdx.x * 4 + (threadIdx.x >> 6);
    int lane = threadIdx.x & 63;
    if (node >= Nn) return;
    int beg = row_ptr[node], end = row_ptr[node + 1];
    float ad = a_dst[node];

    int oh = lane >> 3, cl = lane & 7;
    float acc[8] = {0.f, 0.f, 0.f, 0.f, 0.f, 0.f, 0.f, 0.f};
    float dsum = 0.f;
    const unsigned short* hcol = h2b + cl * 8;
    int j = beg + oh;
    for (; j + 8 < end; j += 16) {
        int s0 = ssrc[j], s1 = ssrc[j + 8];
        float l0 = a_src[s0] + ad; l0 = (l0 > 0.f) ? l0 : NEG_SLOPE * l0;
        float l1 = a_src[s1] + ad; l1 = (l1 > 0.f) ? l1 : NEG_SLOPE * l1;
        float w0 = __expf(l0), w1 = __expf(l1);
        uint4 p0 = *(const uint4*)(hcol + (size_t)s0 * D_OUT);
        uint4 p1 = *(const uint4*)(hcol + (size_t)s1 * D_OUT);
        acc[0] += w0 * bflo(p0.x); acc[1] += w0 * bfhi(p0.x);
        acc[2] += w0 * bflo(p0.y); acc[3] += w0 * bfhi(p0.y);
        acc[4] += w0 * bflo(p0.z); acc[5] += w0 * bfhi(p0.z);
        acc[6] += w0 * bflo(p0.w); acc[7] += w0 * bfhi(p0.w);
        acc[0] += w1 * bflo(p1.x); acc[1] += w1 * bfhi(p1.x);
        acc[2] += w1 * bflo(p1.y); acc[3] += w1 * bfhi(p1.y);
        acc[4] += w1 * bflo(p1.z); acc[5] += w1 * bfhi(p1.z);
        acc[6] += w1 * bflo(p1.w); acc[7] += w1 * bfhi(p1.w);
        if (cl == 0) dsum += w0 + w1;
    }
    for (; j < end; j += 8) {
        int s0 = ssrc[j];
        float l = a_src[s0] + ad; l = (l > 0.f) ? l : NEG_SLOPE * l;
        float w = __expf(l);
        uint4 p = *(const uint4*)(hcol + (size_t)s0 * D_OUT);
        acc[0] += w * bflo(p.x); acc[1] += w * bfhi(p.x);
        acc[2] += w * bflo(p.y); acc[3] += w * bfhi(p.y);
        acc[4] += w * bflo(p.z); acc[5] += w * bfhi(p.z);
        acc[6] += w * bflo(p.w); acc[7] += w * bfhi(p.w);
        if (cl == 0) dsum += w;
    }
    #pragma unroll
    for (int i = 0; i < 8; i++) {
        acc[i] += __shfl_xor(acc[i], 8, 64);
        acc[i] += __shfl_xor(acc[i], 16, 64);
        acc[i] += __shfl_xor(acc[i], 32, 64);
    }
    dsum = wave_reduce_sum(dsum);
    float inv = 1.f / (dsum + 1e-16f);
    if (lane == 0) sminv[node] = inv;

    if (oh == 0) {
        int c = cl * 8;
        uint4 lb = *(const uint4*)(lin2b + (size_t)node * D_OUT + c);
        float4 oa = make_float4(acc[0] * inv + bflo(lb.x), acc[1] * inv + bfhi(lb.x),
                                acc[2] * inv + bflo(lb.y), acc[3] * inv + bfhi(lb.y));
        float4 ob = make_float4(acc[4] * inv + bflo(lb.z), acc[5] * inv + bfhi(lb.z),
                                acc[6] * inv + bflo(lb.w), acc[7] * inv + bfhi(lb.w));
        *(float4*)&out[(size_t)node * D_OUT + c] = oa;
        *(float4*)&out[(size_t)node * D_OUT + c + 4] = ob;
    }
}

// ---- alpha in original edge order ----
__global__ void alpha_kernel(const int* __restrict__ src, const int* __restrict__ dst,
                             const float* __restrict__ a_src2, const float* __restrict__ a_dst2,
                             const float* __restrict__ sminv, float* __restrict__ alpha, int E) {
    int e = blockIdx.x * 256 + threadIdx.x;
    if (e >= E) return;
    int s = src[e], d = dst[e];
    float l = a_src2[s] + a_dst2[d];
    l = (l > 0.f) ? l : NEG_SLOPE * l;
    alpha[e] = __expf(l) * sminv[d];
}

extern "C" void kernel_launch(void* const* d_in, const int* in_sizes, int n_in,
                              void* d_out, int out_size, void* d_ws, size_t ws_size,
                              hipStream_t stream) {
    const float* x        = (const float*)d_in[0];
    const int*   ei       = (const int*)d_in[1];
    const float* W_src1   = (const float*)d_in[2];
    const float* W_dst1   = (const float*)d_in[3];
    const float* att_src1 = (const float*)d_in[4];
    const float* att_dst1 = (const float*)d_in[5];
    const float* b1       = (const float*)d_in[6];
    const float* W_lin1   = (const float*)d_in[7];
    const float* b_lin1   = (const float*)d_in[8];
    const float* W_src2   = (const float*)d_in[9];
    const float* W_dst2   = (const float*)d_in[10];
    const float* att_src2 = (const float*)d_in[11];
    const float* att_dst2 = (const float*)d_in[12];
    const float* b2       = (const float*)d_in[13];
    const float* W_lin2   = (const float*)d_in[14];
    const float* b_lin2   = (const float*)d_in[15];

    const int Nn = in_sizes[0] / D_IN;   // 50000
    const int E  = in_sizes[1] / 2;      // 800000
    const int* src = ei;
    const int* dst = ei + E;

    char* w = (char*)d_ws;
    auto alloc = [&](size_t bytes) { char* p = w; w += (bytes + 255) & ~(size_t)255; return p; };
    unsigned short* h1b  = (unsigned short*)alloc((size_t)Nn * HID * 2);
    unsigned short* lin1b= (unsigned short*)alloc((size_t)Nn * HID * 2);
    unsigned short* hb   = (unsigned short*)alloc((size_t)Nn * HID * 2);
    unsigned short* h2b  = (unsigned short*)alloc((size_t)Nn * D_OUT * 2);
    unsigned short* lin2b= (unsigned short*)alloc((size_t)Nn * D_OUT * 2);
    float* a_src1 = (float*)alloc((size_t)Nn * 4);
    float* a_dst1 = (float*)alloc((size_t)Nn * 4);
    float* a_src2 = (float*)alloc((size_t)Nn * 4);
    float* a_dst2 = (float*)alloc((size_t)Nn * 4);
    float* sminv  = (float*)alloc((size_t)Nn * 4);
    int*   deg    = (int*)alloc((size_t)Nn * 4);
    int*   row_ptr= (int*)alloc((size_t)(Nn + 1) * 4);
    int*   cursor = (int*)alloc((size_t)Nn * 4);
    unsigned short* ssrc = (unsigned short*)alloc((size_t)E * 2);
    short* Wp1    = (short*)alloc((size_t)8 * 16 * 512 * 2);  // 128 KB
    short* Wp2    = (short*)alloc((size_t)4 * 8 * 512 * 2);   // 32 KB
    float* v_src1 = (float*)alloc(D_IN * 4);
    float* v_dst1 = (float*)alloc(D_IN * 4);
    float* v_src2 = (float*)alloc(HID * 4);
    float* v_dst2 = (float*)alloc(HID * 4);
    float* bsum1  = (float*)alloc(HID * 4);
    float* bsum2  = (float*)alloc(D_OUT * 4);
    int*   bsums  = (int*)alloc(64 * 4);
    int*   boff   = (int*)alloc(64 * 4);

    float* out       = (float*)d_out;
    float* alpha_out = out + (size_t)Nn * D_OUT;

    hipMemsetAsync(deg, 0, (size_t)Nn * 4, stream);

    int eblocks = (E + 255) / 256;       // 3125
    fused_pre<<<eblocks + 321, 256, 0, stream>>>(dst, E, deg, eblocks,
                                                 W_src1, W_lin1, Wp1, W_src2, W_lin2, Wp2,
                                                 att_src1, W_dst1, att_dst1,
                                                 att_src2, W_dst2, att_dst2,
                                                 b1, b_lin1, b2, b_lin2,
                                                 v_src1, v_dst1, v_src2, v_dst2, bsum1, bsum2);

    int nb = (Nn + 1023) / 1024;
    scan_partial<<<nb, 1024, 0, stream>>>(deg, Nn, bsums);
    scan_offsets<<<1, 64, 0, stream>>>(bsums, nb, boff);
    scan_final<<<nb, 1024, 0, stream>>>(deg, Nn, boff, row_ptr, cursor);

    int mblocks = (Nn + 63) / 64;        // 782
    // grid must cover: gemm ids 0..781 at bid=5g, scatter ids 0..3124 interleaved
    int bigGrid = 5 * (mblocks - 1) + 2;                 // 3907
    if (bigGrid < eblocks + mblocks) bigGrid = eblocks + mblocks;
    fused_big<<<bigGrid, 256, 0, stream>>>(src, dst, E, cursor, ssrc,
                                           x, Wp1, bsum1, v_src1, v_dst1,
                                           a_src1, a_dst1, h1b, lin1b, Nn, mblocks);

    int ablocks = (Nn + 3) / 4;          // 12500
    agg1_kernel<<<ablocks, 256, 0, stream>>>(row_ptr, ssrc, a_src1, a_dst1, h1b, lin1b,
                                             v_src2, v_dst2, hb, a_src2, a_dst2, Nn);

    gemm_direct<4, 2><<<mblocks, 256, 0, stream>>>(hb, Wp2, bsum2, h2b, lin2b, Nn);
    agg2_kernel<<<ablocks, 256, 0, stream>>>(row_ptr, ssrc, a_src2, a_dst2, h2b, lin2b,
                                             out, sminv, Nn);
    alpha_kernel<<<eblocks, 256, 0, stream>>>(src, dst, a_src2, a_dst2, sminv, alpha_out, E);
}